// Round 11
// baseline (465.591 us; speedup 1.0000x reference)
//
#include <hip/hip_runtime.h>
#include <stdint.h>

typedef short  s16x8 __attribute__((ext_vector_type(8)));
typedef short  s16x4 __attribute__((ext_vector_type(4)));
typedef float  f32x4 __attribute__((ext_vector_type(4)));
typedef unsigned short ushort_t;

#define G_AS __attribute__((address_space(1)))
#define L_AS __attribute__((address_space(3)))

__device__ __forceinline__ void gl_lds16(const void* g, void* l) {
    __builtin_amdgcn_global_load_lds((const G_AS uint32_t*)g, (L_AS uint32_t*)l, 16, 0, 0);
}

__device__ __forceinline__ float b2f(ushort_t u) {
    union { uint32_t i; float f; } v; v.i = ((uint32_t)u) << 16; return v.f;
}
__device__ __forceinline__ ushort_t f2b(float f) {
    uint32_t x = __float_as_uint(f);
    x += 0x7FFF + ((x >> 16) & 1);   // round-to-nearest-even
    return (ushort_t)(x >> 16);
}

#define MFMA16(a, b, c) __builtin_amdgcn_mfma_f32_16x16x32_bf16((a), (b), (c), 0, 0, 0)

// ---------------------------------------------------------------------------
// PREP (one kernel, two independent jobs by block range):
//   blocks [0,768):    transpose+convert up[12][1024][256] f32 -> upT bf16
//   blocks [768,2816): convert x f32 -> xB bf16 (grid-stride, 8 elems/thread)
// ---------------------------------------------------------------------------
__global__ __launch_bounds__(256) void k_prep(const float* __restrict__ up,
                                              ushort_t* __restrict__ upT,
                                              const float* __restrict__ x,
                                              ushort_t* __restrict__ xB) {
    int b = blockIdx.x;
    if (b < 768) {
        int h  = b >> 6;
        int rt = (b >> 2) & 15;
        int ot = b & 3;
        int r0 = rt << 6, o0 = ot << 6;
        __shared__ ushort_t tile[64][72];
        int t = threadIdx.x;
        const float* src = up + ((size_t)h << 18) + (size_t)r0 * 256 + o0;
#pragma unroll
        for (int p = 0; p < 2; ++p) {
            int rr = (t >> 3) + (p << 5);
            int cc = (t & 7) << 3;
            f32x4 va = *(const f32x4*)(src + rr * 256 + cc);
            f32x4 vb = *(const f32x4*)(src + rr * 256 + cc + 4);
#pragma unroll
            for (int j = 0; j < 4; ++j) {
                tile[rr][cc + j]     = f2b(va[j]);
                tile[rr][cc + 4 + j] = f2b(vb[j]);
            }
        }
        __syncthreads();
        ushort_t* dst = upT + ((size_t)h << 18) + (size_t)o0 * 1024 + r0;
#pragma unroll
        for (int p = 0; p < 2; ++p) {
            int oo = (t >> 3) + (p << 5);
            int rr = (t & 7) << 3;
            s16x8 v;
#pragma unroll
            for (int j = 0; j < 8; ++j) v[j] = (short)tile[rr + j][oo];
            *(s16x8*)(dst + (size_t)oo * 1024 + rr) = v;
        }
    } else {
        int idx = (b - 768) * 256 + threadIdx.x;
        int stride = 2048 * 256;
        for (int i = idx; i < 3145728; i += stride) {
            f32x4 a = *(const f32x4*)(x + (size_t)i * 8);
            f32x4 c = *(const f32x4*)(x + (size_t)i * 8 + 4);
            s16x8 v;
#pragma unroll
            for (int j = 0; j < 4; ++j) { v[j] = (short)f2b(a[j]); v[j + 4] = (short)f2b(c[j]); }
            *(s16x8*)(xB + (size_t)i * 8) = v;
        }
    }
}

// ---------------------------------------------------------------------------
// P1: build WT[3072][3072] bf16, WT[h*256+o][g*256+i] = sum_r down[g,i,r]*mix[g,h,r]*up[h,r,o]
// Pure-MFMA inner loop: mix folded into A at STAGE time (reg-staged from f32
// down, scaled, cvt'd, ds_write). B via gl_lds16 from upT (bf16). grid 576.
// ---------------------------------------------------------------------------
__global__ __launch_bounds__(256) void k_build_w(const float* __restrict__ down,
                                                 const float* __restrict__ mixp,
                                                 const ushort_t* __restrict__ upT,
                                                 ushort_t* __restrict__ WT) {
    int bid = blockIdx.x;
    int gh = bid >> 2;
    int g = gh / 12, h = gh % 12;
    int it = (bid >> 1) & 1, ot = bid & 1;
    int i0 = it << 7, o0 = ot << 7;

    const ushort_t* Bt   = upT + ((size_t)h << 18);
    const float*    mrow = mixp + (size_t)gh * 1024;

    __shared__ ushort_t As[128 * 64];
    __shared__ ushort_t Bs[128 * 64];

    int tid  = threadIdx.x;
    int lane = tid & 63, wave = tid >> 6;
    int wr = wave >> 1, wc = wave & 1;
    int lr = lane & 15;
    int kq = (lane >> 4) << 3;

    // A reg-stage assignment: thread t covers row (t>>1), k-half (t&1)*32
    int arow = tid >> 1;
    int akh  = (tid & 1) << 5;
    const float* asrc = down + ((size_t)g << 18) + (size_t)(i0 + arow) * 1024 + akh;
    const float* msrc = mrow + akh;
    ushort_t*    adst = As + arow * 64 + akh;

    f32x4 acc[4][4] = {};

    for (int kk = 0; kk < 1024; kk += 64) {
        __syncthreads();
        // B: async global->LDS (bf16 source)
#pragma unroll
        for (int j = 0; j < 4; ++j) {
            int off = (j << 12) + (tid << 4);
            int row = off >> 7;
            int kc  = (off & 127) >> 1;
            gl_lds16(Bt + (size_t)(o0 + row) * 1024 + kk + kc, (char*)Bs + off);
        }
        // A: reg-stage 32 f32, scale by mix, cvt, 4x ds_write_b128
        {
            f32x4 d[8], mm[8];
#pragma unroll
            for (int j = 0; j < 8; ++j) {
                d[j]  = *(const f32x4*)(asrc + kk + j * 4);
                mm[j] = *(const f32x4*)(msrc + kk + j * 4);
            }
#pragma unroll
            for (int j = 0; j < 4; ++j) {
                s16x8 w;
#pragma unroll
                for (int v = 0; v < 4; ++v) {
                    w[v]     = (short)f2b(d[2 * j][v]     * mm[2 * j][v]);
                    w[v + 4] = (short)f2b(d[2 * j + 1][v] * mm[2 * j + 1][v]);
                }
                *(s16x8*)(adst + j * 8) = w;
            }
        }
        __syncthreads();
#pragma unroll
        for (int ks = 0; ks < 64; ks += 32) {
            s16x8 afr[4], bfr[4];
#pragma unroll
            for (int a = 0; a < 4; ++a)
                afr[a] = *(const s16x8*)&As[(wr * 64 + a * 16 + lr) * 64 + ks + kq];
#pragma unroll
            for (int b = 0; b < 4; ++b)
                bfr[b] = *(const s16x8*)&Bs[(wc * 64 + b * 16 + lr) * 64 + ks + kq];
#pragma unroll
            for (int a = 0; a < 4; ++a)
#pragma unroll
                for (int b = 0; b < 4; ++b)
                    acc[a][b] = MFMA16(afr[a], bfr[b], acc[a][b]);
        }
    }

    int colbase = g * 256 + i0 + wr * 64;
    int rowbase = h * 256 + o0 + wc * 64;
#pragma unroll
    for (int a = 0; a < 4; ++a)
#pragma unroll
        for (int b = 0; b < 4; ++b) {
            int o = rowbase + b * 16 + lr;
            int i = colbase + a * 16 + ((lane >> 4) << 2);
            s16x4 pv;
#pragma unroll
            for (int v = 0; v < 4; ++v) pv[v] = (short)f2b(acc[a][b][v]);
            *(s16x4*)(WT + (size_t)o * 3072 + i) = pv;
        }
}

// ---------------------------------------------------------------------------
// M: 256x256-tile 8-phase GEMM (verified R9; byte-identical).
// ---------------------------------------------------------------------------
#define BAR() __builtin_amdgcn_s_barrier()
#define WAITV(n) asm volatile("s_waitcnt vmcnt(" #n ")" ::: "memory")
#define WAITL() asm volatile("s_waitcnt lgkmcnt(0)" ::: "memory")

__global__ __launch_bounds__(512, 1) void k_main8(const ushort_t* __restrict__ X,
                                                  const ushort_t* __restrict__ WT,
                                                  float* __restrict__ Y) {
    extern __shared__ ushort_t lds[];   // [buf][op][kh][8192]  = 128 KiB
    int bid = blockIdx.x;               // 384 = 8 XCD * 48
    int wg  = (bid & 7) * 48 + (bid >> 3);
    int tt = wg / 12, nt = wg % 12;
    int m0 = tt << 8, n0 = nt << 8;

    int tid  = threadIdx.x;
    int lane = tid & 63;
    int wave = tid >> 6;
    int wr = wave >> 2;          // 0..1
    int wc = wave & 3;           // 0..3
    int lr = lane & 15;
    int cq = lane >> 4;          // k-chunk 0..3

    auto STAGE = [&](int buf, int op, int kh, int t) {
        const ushort_t* src = op ? WT : X;
        int rb = op ? n0 : m0;
        int kb = t * 64 + kh * 32;
        ushort_t* base = lds + buf * 32768 + op * 16384 + kh * 8192;
#pragma unroll
        for (int j = 0; j < 2; ++j) {
            int boff = (j << 13) + (tid << 4);
            int r  = boff >> 6;
            int ch = (boff >> 4) & 3;
            int ks = kb + ((ch ^ ((r >> 1) & 3)) << 3);
            gl_lds16(src + (size_t)(rb + r) * 3072 + ks, (char*)base + boff);
        }
    };
    auto RD = [&](int buf, int op, int kh, int fr) -> s16x8 {
        int row = (op ? wc * 64 : wr * 128) + fr * 16 + lr;
        int off = buf * 32768 + op * 16384 + kh * 8192 + row * 32
                + ((cq ^ ((row >> 1) & 3)) << 3);
        return *(const s16x8*)(lds + off);
    };

    f32x4 acc[8][4] = {};
    s16x8 af[4], bf[4];

#define PH_READ_AB(mlo, kh) { _Pragma("unroll") for (int i = 0; i < 4; ++i) af[i] = RD(cur, 0, kh, (mlo) + i); \
                              _Pragma("unroll") for (int i = 0; i < 4; ++i) bf[i] = RD(cur, 1, kh, i); }
#define PH_READ_A(mlo, kh)  { _Pragma("unroll") for (int i = 0; i < 4; ++i) af[i] = RD(cur, 0, kh, (mlo) + i); }
#define PH_MFMA(mlo)        { __builtin_amdgcn_s_setprio(1); \
                              _Pragma("unroll") for (int mi = 0; mi < 4; ++mi) \
                              _Pragma("unroll") for (int ni = 0; ni < 4; ++ni) \
                                  acc[(mlo) + mi][ni] = MFMA16(af[mi], bf[ni], acc[(mlo) + mi][ni]); \
                              __builtin_amdgcn_s_setprio(0); }

    STAGE(0, 0, 0, 0); STAGE(0, 1, 0, 0); STAGE(0, 0, 1, 0); STAGE(0, 1, 1, 0);
    WAITV(4); BAR();

    int cur = 0;
    for (int t = 0; t < 47; ++t) {
        int nx = cur ^ 1;
        PH_READ_AB(0, 0); STAGE(nx, 0, 0, t + 1);
        BAR(); WAITL(); PH_MFMA(0); BAR();
        PH_READ_A(4, 0);  STAGE(nx, 1, 0, t + 1);
        BAR(); WAITL(); PH_MFMA(4); WAITV(4); BAR();
        PH_READ_AB(0, 1); STAGE(nx, 0, 1, t + 1);
        BAR(); WAITL(); PH_MFMA(0); BAR();
        PH_READ_A(4, 1);  STAGE(nx, 1, 1, t + 1);
        BAR(); WAITL(); PH_MFMA(4); WAITV(4); BAR();
        cur = nx;
    }
    PH_READ_AB(0, 0); BAR(); WAITL(); PH_MFMA(0); BAR();
    PH_READ_A(4, 0);  BAR(); WAITL(); PH_MFMA(4); WAITV(0); BAR();
    PH_READ_AB(0, 1); BAR(); WAITL(); PH_MFMA(0); BAR();
    PH_READ_A(4, 1);  BAR(); WAITL(); PH_MFMA(4);

    int trow = m0 + wr * 128 + (cq << 2);
    int ncol = n0 + wc * 64 + lr;
#pragma unroll
    for (int mi = 0; mi < 8; ++mi)
#pragma unroll
        for (int ni = 0; ni < 4; ++ni) {
            int rr = trow + mi * 16;
            int cc = ncol + ni * 16;
#pragma unroll
            for (int v = 0; v < 4; ++v)
                Y[(size_t)(rr + v) * 3072 + cc] = acc[mi][ni][v];
        }
}

// ---------------------------------------------------------------------------
extern "C" void kernel_launch(void* const* d_in, const int* in_sizes, int n_in,
                              void* d_out, int out_size, void* d_ws, size_t ws_size,
                              hipStream_t stream) {
    const float* x    = (const float*)d_in[0];   // [8192][3072] f32
    const float* down = (const float*)d_in[1];   // [12][256][1024] f32
    const float* mixp = (const float*)d_in[2];   // [12][12][1024] f32
    const float* up   = (const float*)d_in[3];   // [12][1024][256] f32
    float* out = (float*)d_out;                  // [8192][3072] f32

    // ws layout (ushort elems): WT | upT | xB   (~75.5 MB total)
    ushort_t* WT  = (ushort_t*)d_ws;                   // 3072*3072
    ushort_t* upT = WT  + (size_t)3072 * 3072;         // 12*256*1024
    ushort_t* xB  = upT + (size_t)12 * 256 * 1024;     // 8192*3072

    static int lds_attr_set = 0;
    if (!lds_attr_set) {
        hipFuncSetAttribute((const void*)k_main8,
                            hipFuncAttributeMaxDynamicSharedMemorySize, 131072);
        lds_attr_set = 1;
    }

    k_prep   <<<dim3(2816), dim3(256), 0, stream>>>(up, upT, x, xB);
    k_build_w<<<dim3(576),  dim3(256), 0, stream>>>(down, mixp, upT, WT);
    k_main8  <<<dim3(384),  dim3(512), 131072, stream>>>(xB, WT, out);
}